// Round 6
// baseline (139.420 us; speedup 1.0000x reference)
//
#include <hip/hip_runtime.h>

// IMM loss: G=8192 groups of M=16 particles, D=64 dims each, fp32.
// terms = Lap(x,x) + Lap(y,y) - 2*Lap(x,y), Lap = exp(-ws[j]*max(||a-b||,EPS)/D).
//
// R8 == R7 with the compile error fixed: __exp2f is not a HIP intrinsic
// (collided with glibc math.h); use __builtin_amdgcn_exp2f -> v_exp_f32
// (the gfx950 HW op computes 2^x directly; log2(e)/64 pre-folded into s_j).
//
// R7 rationale (untested due to the compile error):
// R6 was latency-bound, not BW-bound (41 us, ~1.6 TB/s effective, WRITE=64KB
// so no spill; per-wave budget 12.3k cyc vs ~3k issue). Fixes:
//  - Occupancy 4 -> 8 waves/SIMD: LDS halved to 4KB/wave by two-phase reuse
//    (stage x -> read xarr -> overwrite same region with y -> read y per
//    granule). Block = 16.4KB, launch_bounds(256,8) (VGPR<=64; R6 used 52).
//  - Cross-lane: xor16 levels via ds_swizzle imm (no index-VGPR, fewer insts);
//    xor32 via __shfl_xor.
//  - exp -> raw v_exp_f32 with log2(e)/64 folded into s_j (one inst per exp).
// All R6-verified mapping/algebra kept verbatim (absmax=0 at R6).

#define EPS_D 0.006f
#define L2E_D64 0.022542110013890053f   // log2(e)/64
#define EXP2(x) __builtin_amdgcn_exp2f(x)

// Rotate within each 16-lane row by O (O = 1..15, compile-time constant).
#define ROT(v, O) __int_as_float(__builtin_amdgcn_update_dpp(              \
        0, __float_as_int(v), 0x120 + (O), 0xF, 0xF, false))

// Butterfly-xor within 32 lanes via ds_swizzle (BitMode: (xor<<10)|0x1F).
#define SWZ(v, PAT) __int_as_float(__builtin_amdgcn_ds_swizzle(            \
        __float_as_int(v), PAT))
#define XOR16(v) SWZ(v, 0x401F)
#define XOR8(v)  SWZ(v, 0x201F)
#define XOR4(v)  SWZ(v, 0x101F)
#define XOR2(v)  SWZ(v, 0x081F)
#define XOR1(v)  SWZ(v, 0x041F)

__global__ __launch_bounds__(256, 8)
void imm_loss_kernel(const float* __restrict__ ys_t,
                     const float* __restrict__ ys_r,
                     const float* __restrict__ w_scale,
                     const float* __restrict__ time_w,
                     float* __restrict__ partials)
{
    const int tid  = threadIdx.x;
    const int lane = tid & 63;
    const int wave = tid >> 6;
    const int g    = blockIdx.x * 4 + wave;   // one group per wave
    const int j    = lane & 15;               // particle index (DPP axis)
    const int db   = lane >> 4;               // dim-quarter 0..3

    // Per-wave LDS: 256 granules (4KB), reused for x then y.
    __shared__ float4 lds4[4][256];           // 16 KB / block
    __shared__ float smem[4];

    const float4* xg = reinterpret_cast<const float4*>(ys_t + (size_t)g * 1024);
    const float4* yg = reinterpret_cast<const float4*>(ys_r + (size_t)g * 1024);

    // Issue ALL global loads up front (one latency exposure).
    // Slot (r,q) receives global granule (r, q^(r&7)) — R6-verified swizzle.
    float4 xs[4], yv[4];
    #pragma unroll
    for (int k = 0; k < 4; ++k) {
        const int r  = 4 * k + db;
        const int gq = j ^ (r & 7);
        xs[k] = xg[r * 16 + gq];
        yv[k] = yg[r * 16 + gq];
    }

    const float s_j = w_scale[g * 16 + j] * L2E_D64;  // ws[j]*log2e/D
    const float tw  = time_w[g * 16];                 // uniform per wave

    // Phase 1: write x, read back this lane's 16 x-dims (R6-verified mapping).
    #pragma unroll
    for (int k = 0; k < 4; ++k) lds4[wave][k * 64 + lane] = xs[k];

    float xarr[16];
    #pragma unroll
    for (int m = 0; m < 4; ++m) {
        const int sl = (db * 4 + m) ^ (j & 7);
        const float4 v = lds4[wave][j * 16 + sl];
        xarr[4*m+0] = v.x; xarr[4*m+1] = v.y; xarr[4*m+2] = v.z; xarr[4*m+3] = v.w;
    }

    // Phase 2: overwrite same LDS with y (compiler orders via lgkm deps).
    #pragma unroll
    for (int k = 0; k < 4; ++k) lds4[wave][k * 64 + lane] = yv[k];

    // Gram accumulators.
    float nx = 0.f, ny = 0.f, g0 = 0.f;
    float gxx[8], gyy[8], gxy[8], hxy[7];
    #pragma unroll
    for (int i = 0; i < 8; ++i) { gxx[i] = 0.f; gyy[i] = 0.f; gxy[i] = 0.f; }
    #pragma unroll
    for (int i = 0; i < 7; ++i) hxy[i] = 0.f;

#define ACC_FULL(O) {                                                      \
            const float xr = ROT(xd, O);                                   \
            const float yr = ROT(yd, O);                                   \
            gxx[(O)-1] = fmaf(xr, xd, gxx[(O)-1]);                         \
            gyy[(O)-1] = fmaf(yr, yd, gyy[(O)-1]);                         \
            gxy[(O)-1] = fmaf(yr, xd, gxy[(O)-1]); }
#define ACC_XY(O) {                                                        \
            const float yr = ROT(yd, O);                                   \
            hxy[(O)-9] = fmaf(yr, xd, hxy[(O)-9]); }

    // Read y granule-at-a-time (4 regs live) and accumulate.
#define GRAM4(M) {                                                         \
        const int sl = (db * 4 + (M)) ^ (j & 7);                           \
        const float4 wv = lds4[wave][j * 16 + sl];                         \
        _Pragma("unroll")                                                  \
        for (int e = 0; e < 4; ++e) {                                      \
            const float xd = xarr[4*(M)+e];                                \
            const float yd = (e == 0) ? wv.x : (e == 1) ? wv.y             \
                           : (e == 2) ? wv.z : wv.w;                       \
            nx = fmaf(xd, xd, nx);                                         \
            ny = fmaf(yd, yd, ny);                                         \
            g0 = fmaf(xd, yd, g0);                                         \
            ACC_FULL(1) ACC_FULL(2) ACC_FULL(3) ACC_FULL(4)                \
            ACC_FULL(5) ACC_FULL(6) ACC_FULL(7) ACC_FULL(8)                \
            ACC_XY(9)  ACC_XY(10) ACC_XY(11) ACC_XY(12)                    \
            ACC_XY(13) ACC_XY(14) ACC_XY(15)                               \
        } }

    GRAM4(0)
    GRAM4(1)
    GRAM4(2)
    GRAM4(3)

    // Reduce partial Gram terms over the 4 dim-quarters (db axis):
    // xor16 (swizzle, within-32) + xor32 (shfl).
#define RED(v) { v += XOR16(v); v += __shfl_xor(v, 32, 64); }
    RED(nx) RED(ny) RED(g0)
    #pragma unroll
    for (int i = 0; i < 8; ++i) { RED(gxx[i]) RED(gyy[i]) RED(gxy[i]) }
    #pragma unroll
    for (int i = 0; i < 7; ++i) { RED(hxy[i]) }

    // ---- Finalize (R6-verified algebra; v_exp_f32 with pre-scaled s_j). ----
    float acc = 2.0f * EXP2(-s_j * EPS_D);

    {
        const float d2 = fmaxf(nx + ny - 2.0f * g0, 0.0f);
        const float dd = fmaxf(sqrtf(d2), EPS_D);
        acc -= 2.0f * EXP2(-s_j * dd);
    }

#define FIN_FULL(O, W) {                                                   \
        const float sk  = ROT(s_j, O);                                     \
        const float nxr = ROT(nx, O);                                      \
        const float nyr = ROT(ny, O);                                      \
        const float ddx = fmaxf(sqrtf(fmaxf(nx + nxr - 2.0f*gxx[(O)-1], 0.f)), EPS_D); \
        const float ddy = fmaxf(sqrtf(fmaxf(ny + nyr - 2.0f*gyy[(O)-1], 0.f)), EPS_D); \
        const float ddz = fmaxf(sqrtf(fmaxf(nx + nyr - 2.0f*gxy[(O)-1], 0.f)), EPS_D); \
        acc += (W) * (EXP2(-s_j * ddx) + EXP2(-sk * ddx));                 \
        acc += (W) * (EXP2(-s_j * ddy) + EXP2(-sk * ddy));                 \
        acc -= 2.0f * EXP2(-s_j * ddz); }

#define FIN_XY(O) {                                                        \
        const float nyr = ROT(ny, O);                                      \
        const float ddz = fmaxf(sqrtf(fmaxf(nx + nyr - 2.0f*hxy[(O)-9], 0.f)), EPS_D); \
        acc -= 2.0f * EXP2(-s_j * ddz); }

    FIN_FULL(1, 1.0f)
    FIN_FULL(2, 1.0f)
    FIN_FULL(3, 1.0f)
    FIN_FULL(4, 1.0f)
    FIN_FULL(5, 1.0f)
    FIN_FULL(6, 1.0f)
    FIN_FULL(7, 1.0f)
    FIN_FULL(8, 0.5f)
    FIN_XY(9)
    FIN_XY(10)
    FIN_XY(11)
    FIN_XY(12)
    FIN_XY(13)
    FIN_XY(14)
    FIN_XY(15)

    // 64-lane butterfly (swizzle for <=16, shfl for 32): sums 16 particles
    // x 4 identical db copies = 4x group sum (folded into host inv_scale).
    float val = acc * tw;
    val += __shfl_xor(val, 32, 64);
    val += XOR16(val);
    val += XOR8(val);
    val += XOR4(val);
    val += XOR2(val);
    val += XOR1(val);

    if (lane == 0) smem[wave] = val;
    __syncthreads();
    if (tid == 0)
        partials[blockIdx.x] = smem[0] + smem[1] + smem[2] + smem[3];
}

__global__ void imm_reduce_kernel(const float* __restrict__ part, int n,
                                  float inv_scale, float* __restrict__ out)
{
    const int tid = threadIdx.x;
    float v = 0.f;
    for (int i = tid; i < n; i += 256) v += part[i];
    #pragma unroll
    for (int off = 32; off; off >>= 1) v += __shfl_xor(v, off, 64);
    __shared__ float s[4];
    if ((tid & 63) == 0) s[tid >> 6] = v;
    __syncthreads();
    if (tid == 0) out[0] = (s[0] + s[1] + s[2] + s[3]) * inv_scale;
}

extern "C" void kernel_launch(void* const* d_in, const int* in_sizes, int n_in,
                              void* d_out, int out_size, void* d_ws, size_t ws_size,
                              hipStream_t stream)
{
    const float* ys_t = (const float*)d_in[0];
    const float* ys_r = (const float*)d_in[1];
    const float* wsc  = (const float*)d_in[2];
    const float* twp  = (const float*)d_in[3];
    float* out      = (float*)d_out;
    float* partials = (float*)d_ws;

    const int B = in_sizes[2];      // 131072 (w_scale element count)
    const int G = B / 16;           // 8192 groups
    const int blocks = G / 4;       // one group per wave, 4 waves per block

    imm_loss_kernel<<<blocks, 256, 0, stream>>>(ys_t, ys_r, wsc, twp, partials);

    // Sum of partials = 4 * sum_g(tw_g * terms_g); divide by M*M*G and the 4.
    const float inv_scale = 1.0f / (1024.0f * (float)G);
    imm_reduce_kernel<<<1, 256, 0, stream>>>(partials, blocks, inv_scale, out);
}

// Round 7
// 119.343 us; speedup vs baseline: 1.1682x; 1.1682x over previous
//
#include <hip/hip_runtime.h>

// IMM loss: G=8192 groups of M=16 particles, D=64 dims each, fp32.
// terms = Lap(x,x) + Lap(y,y) - 2*Lap(x,y), Lap = exp(-ws[j]*max(||a-b||,EPS)/D).
//
// R9: R8's launch_bounds(256,8) capped VGPR at 64 < ~75 live set -> compiler
// spilled ~135B/thread to scratch (WRITE_SIZE 70.8 MB on an 8 KB-output
// kernel), 56 us. Fix: the spill-free occupancy point.
//  - launch_bounds(256,6): VGPR cap 85 >= live set, 24 waves/CU, no spill.
//  - y global loads DEFERRED until after xarr readback (don't hold yv[4]
//    float4s across phase 1): peak live ~60 regs. Exposed y latency is one
//    round-trip per wave, hidden by 6-wave TLP.
//  - Bank conflicts measured negligible (262k cyc = 0.3%): swizzle verified.
// All R6/R8-verified mapping/algebra byte-identical (absmax=0 both rounds).

#define EPS_D 0.006f
#define L2E_D64 0.022542110013890053f   // log2(e)/64
#define EXP2(x) __builtin_amdgcn_exp2f(x)

// Rotate within each 16-lane row by O (O = 1..15, compile-time constant).
#define ROT(v, O) __int_as_float(__builtin_amdgcn_update_dpp(              \
        0, __float_as_int(v), 0x120 + (O), 0xF, 0xF, false))

// Butterfly-xor within 32 lanes via ds_swizzle (BitMode: (xor<<10)|0x1F).
#define SWZ(v, PAT) __int_as_float(__builtin_amdgcn_ds_swizzle(            \
        __float_as_int(v), PAT))
#define XOR16(v) SWZ(v, 0x401F)
#define XOR8(v)  SWZ(v, 0x201F)
#define XOR4(v)  SWZ(v, 0x101F)
#define XOR2(v)  SWZ(v, 0x081F)
#define XOR1(v)  SWZ(v, 0x041F)

__global__ __launch_bounds__(256, 6)
void imm_loss_kernel(const float* __restrict__ ys_t,
                     const float* __restrict__ ys_r,
                     const float* __restrict__ w_scale,
                     const float* __restrict__ time_w,
                     float* __restrict__ partials)
{
    const int tid  = threadIdx.x;
    const int lane = tid & 63;
    const int wave = tid >> 6;
    const int g    = blockIdx.x * 4 + wave;   // one group per wave
    const int j    = lane & 15;               // particle index (DPP axis)
    const int db   = lane >> 4;               // dim-quarter 0..3

    // Per-wave LDS: 256 granules (4KB), reused for x then y.
    __shared__ float4 lds4[4][256];           // 16 KB / block
    __shared__ float smem[4];

    const float4* xg = reinterpret_cast<const float4*>(ys_t + (size_t)g * 1024);
    const float4* yg = reinterpret_cast<const float4*>(ys_r + (size_t)g * 1024);

    const float s_j = w_scale[g * 16 + j] * L2E_D64;  // ws[j]*log2e/D
    const float tw  = time_w[g * 16];                 // uniform per wave

    // Phase 1: load x (coalesced, swizzled source: slot (r,q) gets global
    // granule (r, q^(r&7)) — R6-verified), write LDS, read back this lane's
    // 16 x-dims.
    {
        float4 xs[4];
        #pragma unroll
        for (int k = 0; k < 4; ++k) {
            const int r  = 4 * k + db;
            const int gq = j ^ (r & 7);
            xs[k] = xg[r * 16 + gq];
        }
        #pragma unroll
        for (int k = 0; k < 4; ++k) lds4[wave][k * 64 + lane] = xs[k];
    }

    float xarr[16];
    #pragma unroll
    for (int m = 0; m < 4; ++m) {
        const int sl = (db * 4 + m) ^ (j & 7);
        const float4 v = lds4[wave][j * 16 + sl];
        xarr[4*m+0] = v.x; xarr[4*m+1] = v.y; xarr[4*m+2] = v.z; xarr[4*m+3] = v.w;
    }

    // Phase 2: load y (deferred — not held across phase 1), overwrite same
    // LDS region (compiler orders via lgkm deps; wave-local, no barrier).
    {
        float4 yv[4];
        #pragma unroll
        for (int k = 0; k < 4; ++k) {
            const int r  = 4 * k + db;
            const int gq = j ^ (r & 7);
            yv[k] = yg[r * 16 + gq];
        }
        #pragma unroll
        for (int k = 0; k < 4; ++k) lds4[wave][k * 64 + lane] = yv[k];
    }

    // Gram accumulators.
    float nx = 0.f, ny = 0.f, g0 = 0.f;
    float gxx[8], gyy[8], gxy[8], hxy[7];
    #pragma unroll
    for (int i = 0; i < 8; ++i) { gxx[i] = 0.f; gyy[i] = 0.f; gxy[i] = 0.f; }
    #pragma unroll
    for (int i = 0; i < 7; ++i) hxy[i] = 0.f;

#define ACC_FULL(O) {                                                      \
            const float xr = ROT(xd, O);                                   \
            const float yr = ROT(yd, O);                                   \
            gxx[(O)-1] = fmaf(xr, xd, gxx[(O)-1]);                         \
            gyy[(O)-1] = fmaf(yr, yd, gyy[(O)-1]);                         \
            gxy[(O)-1] = fmaf(yr, xd, gxy[(O)-1]); }
#define ACC_XY(O) {                                                        \
            const float yr = ROT(yd, O);                                   \
            hxy[(O)-9] = fmaf(yr, xd, hxy[(O)-9]); }

    // Read y granule-at-a-time (4 regs live) and accumulate.
#define GRAM4(M) {                                                         \
        const int sl = (db * 4 + (M)) ^ (j & 7);                           \
        const float4 wv = lds4[wave][j * 16 + sl];                         \
        _Pragma("unroll")                                                  \
        for (int e = 0; e < 4; ++e) {                                      \
            const float xd = xarr[4*(M)+e];                                \
            const float yd = (e == 0) ? wv.x : (e == 1) ? wv.y             \
                           : (e == 2) ? wv.z : wv.w;                       \
            nx = fmaf(xd, xd, nx);                                         \
            ny = fmaf(yd, yd, ny);                                         \
            g0 = fmaf(xd, yd, g0);                                         \
            ACC_FULL(1) ACC_FULL(2) ACC_FULL(3) ACC_FULL(4)                \
            ACC_FULL(5) ACC_FULL(6) ACC_FULL(7) ACC_FULL(8)                \
            ACC_XY(9)  ACC_XY(10) ACC_XY(11) ACC_XY(12)                    \
            ACC_XY(13) ACC_XY(14) ACC_XY(15)                               \
        } }

    GRAM4(0)
    GRAM4(1)
    GRAM4(2)
    GRAM4(3)

    // Reduce partial Gram terms over the 4 dim-quarters (db axis):
    // xor16 (swizzle, within-32) + xor32 (shfl).
#define RED(v) { v += XOR16(v); v += __shfl_xor(v, 32, 64); }
    RED(nx) RED(ny) RED(g0)
    #pragma unroll
    for (int i = 0; i < 8; ++i) { RED(gxx[i]) RED(gyy[i]) RED(gxy[i]) }
    #pragma unroll
    for (int i = 0; i < 7; ++i) { RED(hxy[i]) }

    // ---- Finalize (R6-verified algebra; v_exp_f32 with pre-scaled s_j). ----
    float acc = 2.0f * EXP2(-s_j * EPS_D);

    {
        const float d2 = fmaxf(nx + ny - 2.0f * g0, 0.0f);
        const float dd = fmaxf(sqrtf(d2), EPS_D);
        acc -= 2.0f * EXP2(-s_j * dd);
    }

#define FIN_FULL(O, W) {                                                   \
        const float sk  = ROT(s_j, O);                                     \
        const float nxr = ROT(nx, O);                                      \
        const float nyr = ROT(ny, O);                                      \
        const float ddx = fmaxf(sqrtf(fmaxf(nx + nxr - 2.0f*gxx[(O)-1], 0.f)), EPS_D); \
        const float ddy = fmaxf(sqrtf(fmaxf(ny + nyr - 2.0f*gyy[(O)-1], 0.f)), EPS_D); \
        const float ddz = fmaxf(sqrtf(fmaxf(nx + nyr - 2.0f*gxy[(O)-1], 0.f)), EPS_D); \
        acc += (W) * (EXP2(-s_j * ddx) + EXP2(-sk * ddx));                 \
        acc += (W) * (EXP2(-s_j * ddy) + EXP2(-sk * ddy));                 \
        acc -= 2.0f * EXP2(-s_j * ddz); }

#define FIN_XY(O) {                                                        \
        const float nyr = ROT(ny, O);                                      \
        const float ddz = fmaxf(sqrtf(fmaxf(nx + nyr - 2.0f*hxy[(O)-9], 0.f)), EPS_D); \
        acc -= 2.0f * EXP2(-s_j * ddz); }

    FIN_FULL(1, 1.0f)
    FIN_FULL(2, 1.0f)
    FIN_FULL(3, 1.0f)
    FIN_FULL(4, 1.0f)
    FIN_FULL(5, 1.0f)
    FIN_FULL(6, 1.0f)
    FIN_FULL(7, 1.0f)
    FIN_FULL(8, 0.5f)
    FIN_XY(9)
    FIN_XY(10)
    FIN_XY(11)
    FIN_XY(12)
    FIN_XY(13)
    FIN_XY(14)
    FIN_XY(15)

    // 64-lane butterfly (swizzle for <=16, shfl for 32): sums 16 particles
    // x 4 identical db copies = 4x group sum (folded into host inv_scale).
    float val = acc * tw;
    val += __shfl_xor(val, 32, 64);
    val += XOR16(val);
    val += XOR8(val);
    val += XOR4(val);
    val += XOR2(val);
    val += XOR1(val);

    if (lane == 0) smem[wave] = val;
    __syncthreads();
    if (tid == 0)
        partials[blockIdx.x] = smem[0] + smem[1] + smem[2] + smem[3];
}

__global__ void imm_reduce_kernel(const float* __restrict__ part, int n,
                                  float inv_scale, float* __restrict__ out)
{
    const int tid = threadIdx.x;
    float v = 0.f;
    for (int i = tid; i < n; i += 256) v += part[i];
    #pragma unroll
    for (int off = 32; off; off >>= 1) v += __shfl_xor(v, off, 64);
    __shared__ float s[4];
    if ((tid & 63) == 0) s[tid >> 6] = v;
    __syncthreads();
    if (tid == 0) out[0] = (s[0] + s[1] + s[2] + s[3]) * inv_scale;
}

extern "C" void kernel_launch(void* const* d_in, const int* in_sizes, int n_in,
                              void* d_out, int out_size, void* d_ws, size_t ws_size,
                              hipStream_t stream)
{
    const float* ys_t = (const float*)d_in[0];
    const float* ys_r = (const float*)d_in[1];
    const float* wsc  = (const float*)d_in[2];
    const float* twp  = (const float*)d_in[3];
    float* out      = (float*)d_out;
    float* partials = (float*)d_ws;

    const int B = in_sizes[2];      // 131072 (w_scale element count)
    const int G = B / 16;           // 8192 groups
    const int blocks = G / 4;       // one group per wave, 4 waves per block

    imm_loss_kernel<<<blocks, 256, 0, stream>>>(ys_t, ys_r, wsc, twp, partials);

    // Sum of partials = 4 * sum_g(tw_g * terms_g); divide by M*M*G and the 4.
    const float inv_scale = 1.0f / (1024.0f * (float)G);
    imm_reduce_kernel<<<1, 256, 0, stream>>>(partials, blocks, inv_scale, out);
}